// Round 16
// baseline (126.342 us; speedup 1.0000x reference)
//
#include <hip/hip_runtime.h>
#include <hip/hip_cooperative_groups.h>

namespace cg = cooperative_groups;

// B=4096, F0=39, D=16, L=(128,128), H1=64
// Round-16: r15 fused cooperative kernel, correctness-hardened:
//  (1) fused kernel __launch_bounds__(256,4): VGPR cap 128 -> >=4 blocks/CU ->
//      1024 blocks co-resident (r15 likely failed the co-residency check at
//      (256,2) with >128 VGPR and the error was silently dropped);
//  (2) occupancy pre-check before attempting cooperative launch;
//  (3) error-checked fallback to the exact r14 two-kernel path (guaranteed pass).
// Structure (both paths): mfma_f32_32x32x16_f16, M=32=2 batches x 16 d, N=128,
// folded K (L0 upper-tri 30 + L1 80 = 110 chunks), xw regs, dist-4 B prefetch,
// no K-loop barriers. Repack: f16 frag-order d_ws with layer-0 symmetric fold.
// Layouts (verified): A: lane A[m=lane&31][k=(lane>>5)*8+t]; B: B[k=(lane>>5)*8+t][n=lane&31];
//  D: D[row=(r&3)+8*(r>>2)+4*(lane>>5)][col=lane&31]
// Repacked B (BYTES): ch*8192 + kh*4096 + cg*1024 + lane*16; total 901,120 B.

typedef _Float16 h2    __attribute__((ext_vector_type(2)));
typedef _Float16 f16x8 __attribute__((ext_vector_type(8)));
typedef __attribute__((ext_vector_type(16))) float f32x16;

#define XBB 1160   // per-batch halfs in xsH: 16 rows * 72 + 8 skew (2320 B, 16-aligned)
#define L0C 30
#define NCH 110

__device__ __constant__ int IG0[L0C] = {0,0,0,0,0, 1,1,1,1,1, 2,2,2,2, 3,3,3,3, 4,4,4, 5,5,5, 6,6, 7,7, 8, 9};
__device__ __constant__ int JG0[L0C] = {0,1,2,3,4, 0,1,2,3,4, 1,2,3,4, 1,2,3,4, 2,3,4, 2,3,4, 3,4, 3,4, 4, 4};
#define IG0T(c) ((c)<5?0:(c)<10?1:(c)<14?2:(c)<18?3:(c)<21?4:(c)<24?5:(c)<26?6:(c)<28?7:(c)<29?8:9)
#define JG0T(c) ((c)<10?((c)%5):(c)<18?(((c)-10)%4+1):(c)<24?(((c)-18)%3+2):(c)<28?(((c)-24)%2+3):4)

// ---------------- device helper: repack one gtid slot ----------------
static __device__ __forceinline__ void repack_slot(int gtid,
                                                   const float* __restrict__ f0,
                                                   const float* __restrict__ f1,
                                                   uint4* __restrict__ ws)
{
    const int n    = gtid & 127;
    const int slot = gtid >> 7;
    const int half = slot & 1;
    const int kh   = (slot >> 1) & 1;
    const int ch   = slot >> 2;                         // 0..109
    float v[8];
    if (ch < L0C) {
        const int ig = IG0[ch], jg = JG0[ch];
        const int i = ig * 4 + kh * 2 + half;
#pragma unroll
        for (int t = 0; t < 8; ++t) {
            const int j = jg * 8 + t;
            float val = 0.f;
            if (i < 39 && j < 39 && j >= i) {
                val = f0[(i * 39 + j) * 128 + n];
                if (j > i) val += f0[(j * 39 + i) * 128 + n];   // symmetric fold
            }
            v[t] = val;
        }
    } else {
        const int c1 = ch - L0C;
        const int jg = c1 / 5, ig = c1 - jg * 5;
        const int j = jg * 4 + kh * 2 + half;
#pragma unroll
        for (int t = 0; t < 8; ++t) {
            const int i = ig * 8 + t;
            v[t] = (i < 39) ? f1[(i * 64 + j) * 128 + n] : 0.f;
        }
    }
    union { h2 h[4]; uint4 q; } pk;
#pragma unroll
    for (int t = 0; t < 4; ++t)
        pk.h[t] = h2{(_Float16)v[2 * t], (_Float16)v[2 * t + 1]};
    const int lane = half * 32 + (n & 31);
    const int cg   = n >> 5;
    ws[ch * 512 + kh * 256 + cg * 64 + lane] = pk.q;
}

// ---------------- device helper: the whole main body (phase 2) ----------------
static __device__ __forceinline__ void main_body(
    const float* __restrict__ x, const char* __restrict__ wsB,
    const float* __restrict__ dw, const float* __restrict__ db,
    float* __restrict__ out,
    _Float16* xsH, _Float16* hsH /*[4][64][18]*/, float* dws, float* red /*[4][4]*/,
    bool stage_x)
{
    const int tid  = threadIdx.x;
    const int w    = tid >> 6;
    const int lane = tid & 63;
    const int half = lane >> 5;
    const int d    = lane & 15;
    const int bsel = (lane >> 4) & 1;
    const int col  = lane & 31;

    if (stage_x) {
        const float4* xg4 = (const float4*)(x + (size_t)blockIdx.x * 4 * 624);
        for (int e4 = tid; e4 < 624; e4 += 256) {
            float4 v = xg4[e4];
            int bb = e4 / 156, r = e4 - bb * 156;
            int i = r >> 2, d0 = (r & 3) * 4;
            _Float16* bp = xsH + bb * XBB + i;
            bp[(d0 + 0) * 72] = (_Float16)v.x; bp[(d0 + 1) * 72] = (_Float16)v.y;
            bp[(d0 + 2) * 72] = (_Float16)v.z; bp[(d0 + 3) * 72] = (_Float16)v.w;
        }
        if (tid < 64) { int bb = tid >> 4, dd = tid & 15; xsH[bb * XBB + dd * 72 + 39] = (_Float16)0.f; }
        if (tid < 192) dws[tid] = dw[tid];
        __syncthreads();
    }

    const _Float16* xrow[2] = { xsH + bsel * XBB + d * 72, xsH + (2 + bsel) * XBB + d * 72 };

    h2 xw[2][20];
#pragma unroll
    for (int p = 0; p < 2; ++p)
#pragma unroll
        for (int w5 = 0; w5 < 5; ++w5) {
            union { f16x8 v; h2 h[4]; } u;
            u.v = *(const f16x8*)(xrow[p] + w5 * 8);
#pragma unroll
            for (int q = 0; q < 4; ++q) xw[p][w5 * 4 + q] = u.h[q];
        }

    const char* wbase = wsB + lane * 16 + w * 1024 + 2048;
    f16x8 Bb[4][2];
    auto loadBg = [&](int ch, f16x8 (&B)[2]) {
        const char* p0 = wbase + (size_t)ch * 8192;
        B[0] = *(const f16x8*)(p0 - 2048);
        B[1] = *(const f16x8*)(p0 + 2048);
    };
    loadBg(0, Bb[0]); loadBg(1, Bb[1]); loadBg(2, Bb[2]); loadBg(3, Bb[3]);

    f32x16 acc[2];
#pragma unroll
    for (int p = 0; p < 2; ++p)
#pragma unroll
        for (int r = 0; r < 16; ++r) acc[p][r] = 0.f;

    h2 sp2[2][2];

    // ---- layer 0: 30 folded chunks, fully unrolled, phase = c&3 ----
#pragma unroll
    for (int c = 0; c < L0C; ++c) {
        const int ig = IG0T(c);
        const int jg = JG0T(c);
        if ((c == 0) || (IG0T(c) != IG0T(c - 1))) {
#pragma unroll
            for (int p = 0; p < 2; ++p)
#pragma unroll
                for (int kh = 0; kh < 2; ++kh) {
                    const h2 pr = xw[p][ig * 2 + kh];
                    const _Float16 vv = half ? pr.y : pr.x;
                    sp2[p][kh] = h2{vv, vv};
                }
        }
#pragma unroll
        for (int p = 0; p < 2; ++p) {
            union { h2 h[4]; f16x8 v; } a0, a1;
#pragma unroll
            for (int q = 0; q < 4; ++q) {
                a0.h[q] = sp2[p][0] * xw[p][jg * 4 + q];
                a1.h[q] = sp2[p][1] * xw[p][jg * 4 + q];
            }
            acc[p] = __builtin_amdgcn_mfma_f32_32x32x16_f16(a0.v, Bb[c & 3][0], acc[p], 0, 0, 0);
            acc[p] = __builtin_amdgcn_mfma_f32_32x32x16_f16(a1.v, Bb[c & 3][1], acc[p], 0, 0, 0);
        }
        loadBg(c + 4, Bb[c & 3]);
    }

    // ---- layer-0 epilogue ----
    float cs[4] = {0.f, 0.f, 0.f, 0.f};
    if (w < 2) {
#pragma unroll
        for (int p = 0; p < 2; ++p)
#pragma unroll
            for (int r = 0; r < 16; r += 2) {
                const int row = (r & 3) + 8 * (r >> 2) + 4 * half;
                h2 pr = h2{(_Float16)fmaxf(acc[p][r],     0.f),
                           (_Float16)fmaxf(acc[p][r + 1], 0.f)};
                *(h2*)&hsH[(p * 2 + (row >> 4)) * (64 * 18) + (w * 32 + col) * 18 + (row & 15)] = pr;
            }
    } else {
        const float dwv = dws[(w - 2) * 32 + col];
#pragma unroll
        for (int p = 0; p < 2; ++p)
#pragma unroll
            for (int r = 0; r < 16; ++r) {
                const int row = (r & 3) + 8 * (r >> 2) + 4 * half;
                cs[p * 2 + (row >> 4)] += fmaxf(acc[p][r], 0.f) * dwv;
            }
    }
#pragma unroll
    for (int p = 0; p < 2; ++p)
#pragma unroll
        for (int r = 0; r < 16; ++r) acc[p][r] = 0.f;
    __syncthreads();

    // ---- layer 1: 4 outer x 20 unrolled chunks (30..109), phase=(2+u)&3 ----
#pragma unroll 1
    for (int o2 = 0; o2 < 4; ++o2) {
#pragma unroll
        for (int u = 0; u < 20; ++u) {
            const int ig2 = u % 5;
            if (ig2 == 0) {
                const int jb = (o2 * 4 + u / 5) * 4;
#pragma unroll
                for (int p = 0; p < 2; ++p)
#pragma unroll
                    for (int kh = 0; kh < 2; ++kh) {
                        const _Float16 s =
                            hsH[(p * 2 + bsel) * (64 * 18) + (jb + kh * 2 + half) * 18 + d];
                        sp2[p][kh] = h2{s, s};
                    }
            }
#pragma unroll
            for (int p = 0; p < 2; ++p) {
                union { h2 h[4]; f16x8 v; } a0, a1;
#pragma unroll
                for (int q = 0; q < 4; ++q) {
                    a0.h[q] = sp2[p][0] * xw[p][ig2 * 4 + q];
                    a1.h[q] = sp2[p][1] * xw[p][ig2 * 4 + q];
                }
                acc[p] = __builtin_amdgcn_mfma_f32_32x32x16_f16(a0.v, Bb[(2 + u) & 3][0], acc[p], 0, 0, 0);
                acc[p] = __builtin_amdgcn_mfma_f32_32x32x16_f16(a1.v, Bb[(2 + u) & 3][1], acc[p], 0, 0, 0);
            }
            int chn = 30 + o2 * 20 + u + 4; if (chn > NCH - 1) chn = NCH - 1;
            loadBg(chn, Bb[(2 + u) & 3]);
        }
    }

    // ---- layer-1 epilogue + reduction ----
    {
        const float dwv = dws[64 + w * 32 + col];
#pragma unroll
        for (int p = 0; p < 2; ++p)
#pragma unroll
            for (int r = 0; r < 16; ++r) {
                const int row = (r & 3) + 8 * (r >> 2) + 4 * half;
                cs[p * 2 + (row >> 4)] += fmaxf(acc[p][r], 0.f) * dwv;
            }
    }
#pragma unroll
    for (int rr = 0; rr < 4; ++rr)
#pragma unroll
        for (int off = 32; off > 0; off >>= 1)
            cs[rr] += __shfl_xor(cs[rr], off, 64);
    if (lane == 0) {
#pragma unroll
        for (int rr = 0; rr < 4; ++rr) red[w * 4 + rr] = cs[rr];
    }
    __syncthreads();
    if (tid < 4)
        out[blockIdx.x * 4 + tid] = red[0 + tid] + red[4 + tid] + red[8 + tid] + red[12 + tid] + db[0];
}

// ---------------- fallback kernel 1: repack ----------------
__global__ __launch_bounds__(256)
void CIN_repack(const float* __restrict__ f0, const float* __restrict__ f1,
                uint4* __restrict__ ws)
{
    const int gtid = blockIdx.x * 256 + threadIdx.x;   // 56320 total
    if (gtid < 56320) repack_slot(gtid, f0, f1, ws);
}

// ---------------- fallback kernel 2: main (r14) ----------------
__global__ __launch_bounds__(256, 2)
void CIN_main(const float* __restrict__ x, const char* __restrict__ wsB,
              const float* __restrict__ dw, const float* __restrict__ db,
              float* __restrict__ out)
{
    __shared__ __align__(16) _Float16 xsH[4 * XBB];
    __shared__ __align__(4)  _Float16 hsH[4 * 64 * 18];
    __shared__ float dws[192];
    __shared__ float red[16];
    main_body(x, wsB, dw, db, out, xsH, hsH, dws, red, true);
}

// ---------------- fused cooperative kernel ----------------
__global__ __launch_bounds__(256, 4)
void CIN_fused(const float* __restrict__ x,
               const float* __restrict__ f0,
               const float* __restrict__ f1,
               const float* __restrict__ dw,
               const float* __restrict__ db,
               uint4* __restrict__ ws,
               float* __restrict__ out)
{
    __shared__ __align__(16) _Float16 xsH[4 * XBB];
    __shared__ __align__(4)  _Float16 hsH[4 * 64 * 18];
    __shared__ float dws[192];
    __shared__ float red[16];

    const int tid  = threadIdx.x;
    const int gtid = blockIdx.x * 256 + tid;

    // phase 1a: repack share (first 220 blocks)
    if (gtid < 56320) repack_slot(gtid, f0, f1, ws);

    // phase 1b: stage x for this block's 4 batches (also hides repack latency)
    {
        const float4* xg4 = (const float4*)(x + (size_t)blockIdx.x * 4 * 624);
        for (int e4 = tid; e4 < 624; e4 += 256) {
            float4 v = xg4[e4];
            int bb = e4 / 156, r = e4 - bb * 156;
            int i = r >> 2, d0 = (r & 3) * 4;
            _Float16* bp = xsH + bb * XBB + i;
            bp[(d0 + 0) * 72] = (_Float16)v.x; bp[(d0 + 1) * 72] = (_Float16)v.y;
            bp[(d0 + 2) * 72] = (_Float16)v.z; bp[(d0 + 3) * 72] = (_Float16)v.w;
        }
        if (tid < 64) { int bb = tid >> 4, dd = tid & 15; xsH[bb * XBB + dd * 72 + 39] = (_Float16)0.f; }
        if (tid < 192) dws[tid] = dw[tid];
    }
    __syncthreads();

    // grid-wide sync: ws fully written & visible
    __threadfence();
    cg::this_grid().sync();
    __threadfence();

    main_body(x, (const char*)ws, dw, db, out, xsH, hsH, dws, red, false);
}

extern "C" void kernel_launch(void* const* d_in, const int* in_sizes, int n_in,
                              void* d_out, int out_size, void* d_ws, size_t ws_size,
                              hipStream_t stream)
{
    const float* x  = (const float*)d_in[0];
    const float* f0 = (const float*)d_in[1];
    const float* f1 = (const float*)d_in[2];
    const float* dw = (const float*)d_in[3];
    const float* db = (const float*)d_in[4];
    float* out = (float*)d_out;
    uint4* ws = (uint4*)d_ws;

    // co-residency pre-check for the cooperative path (pure queries, capture-safe)
    int dev = 0;
    (void)hipGetDevice(&dev);
    int numCU = 0;
    (void)hipDeviceGetAttribute(&numCU, hipDeviceAttributeMultiprocessorCount, dev);
    int maxBlk = 0;
    hipError_t qe = hipOccupancyMaxActiveBlocksPerMultiprocessor(&maxBlk, CIN_fused, 256, 0);

    hipError_t le = hipErrorUnknown;
    if (qe == hipSuccess && numCU > 0 && maxBlk * numCU >= 1024) {
        void* args[] = { (void*)&x, (void*)&f0, (void*)&f1, (void*)&dw,
                         (void*)&db, (void*)&ws, (void*)&out };
        le = hipLaunchCooperativeKernel(CIN_fused, dim3(1024), dim3(256),
                                        args, 0, stream);
    }
    if (le != hipSuccess) {
        // fallback: exact r14 two-kernel path
        CIN_repack<<<dim3(220), dim3(256), 0, stream>>>(f0, f1, ws);
        CIN_main<<<dim3(1024), dim3(256), 0, stream>>>(x, (const char*)ws, dw, db, out);
    }
}

// Round 17
// 123.946 us; speedup vs baseline: 1.0193x; 1.0193x over previous
//
#include <hip/hip_runtime.h>

// B=4096, F0=39, D=16, L=(128,128), H1=64
// Round-17: r14 with SPLIT ACCUMULATORS — the one untested hypothesis.
//  - In r6-r16 each acc[p] received 2 chained MFMAs/chunk (kh0->kh1 same dest) and
//    chained across all 110 chunks; if mfma result->C latency ~64+ cyc this is a
//    ~128 cyc/chunk per-wave critical path that no amount of TLP/ILP/BW tested so
//    far removes (MfmaUtil pinned 37-48% across 8 orthogonal levers).
//  - Fix: accA[p] (kh=0) and accB[p] (kh=1), merged in epilogue (z = accA+accB,
//    exact — both are partial K-sums). All 4 MFMAs per chunk independent.
//  - Everything else identical to r14: mfma_f32_32x32x16_f16, M=32=2 batches x 16 d,
//    N=128, folded K (L0 upper-tri 30 + L1 80 = 110 chunks), xw regs, dist-4 B
//    prefetch, no K-loop barriers, two-kernel launch (repack + main).
// Layouts (verified): A: lane A[m=lane&31][k=(lane>>5)*8+t]; B: B[k=(lane>>5)*8+t][n=lane&31];
//  D: D[row=(r&3)+8*(r>>2)+4*(lane>>5)][col=lane&31]
// Repacked B (BYTES): ch*8192 + kh*4096 + cg*1024 + lane*16
//  L0 ch=0..29 (IG0/JG0): i=ig*4+kh*2+half, j=jg*8+t; folded (W'[i,j]=W[i,j]+W[j,i], j>i).
//  L1 ch=30+jg*5+ig: j=jg*4+kh*2+half, i=ig*8+t, zero-pad i>=39.  Total 901,120 B.

typedef _Float16 h2    __attribute__((ext_vector_type(2)));
typedef _Float16 f16x8 __attribute__((ext_vector_type(8)));
typedef __attribute__((ext_vector_type(16))) float f32x16;

#define XBB 1160   // per-batch halfs in xsH: 16 rows * 72 + 8 skew (2320 B, 16-aligned)
#define L0C 30
#define NCH 110

__device__ __constant__ int IG0[L0C] = {0,0,0,0,0, 1,1,1,1,1, 2,2,2,2, 3,3,3,3, 4,4,4, 5,5,5, 6,6, 7,7, 8, 9};
__device__ __constant__ int JG0[L0C] = {0,1,2,3,4, 0,1,2,3,4, 1,2,3,4, 1,2,3,4, 2,3,4, 2,3,4, 3,4, 3,4, 4, 4};
#define IG0T(c) ((c)<5?0:(c)<10?1:(c)<14?2:(c)<18?3:(c)<21?4:(c)<24?5:(c)<26?6:(c)<28?7:(c)<29?8:9)
#define JG0T(c) ((c)<10?((c)%5):(c)<18?(((c)-10)%4+1):(c)<24?(((c)-18)%3+2):(c)<28?(((c)-24)%2+3):4)

// ---------------- weight repack (unchanged) ----------------
__global__ __launch_bounds__(256)
void CIN_repack(const float* __restrict__ f0, const float* __restrict__ f1,
                uint4* __restrict__ ws)
{
    const int tid  = blockIdx.x * 256 + threadIdx.x;   // 56320 total
    const int n    = tid & 127;
    const int slot = tid >> 7;
    const int half = slot & 1;
    const int kh   = (slot >> 1) & 1;
    const int ch   = slot >> 2;                         // 0..109
    float v[8];
    if (ch < L0C) {
        const int ig = IG0[ch], jg = JG0[ch];
        const int i = ig * 4 + kh * 2 + half;
#pragma unroll
        for (int t = 0; t < 8; ++t) {
            const int j = jg * 8 + t;
            float val = 0.f;
            if (i < 39 && j < 39 && j >= i) {
                val = f0[(i * 39 + j) * 128 + n];
                if (j > i) val += f0[(j * 39 + i) * 128 + n];   // symmetric fold
            }
            v[t] = val;
        }
    } else {
        const int c1 = ch - L0C;
        const int jg = c1 / 5, ig = c1 - jg * 5;
        const int j = jg * 4 + kh * 2 + half;
#pragma unroll
        for (int t = 0; t < 8; ++t) {
            const int i = ig * 8 + t;
            v[t] = (i < 39) ? f1[(i * 64 + j) * 128 + n] : 0.f;
        }
    }
    union { h2 h[4]; uint4 q; } pk;
#pragma unroll
    for (int t = 0; t < 4; ++t)
        pk.h[t] = h2{(_Float16)v[2 * t], (_Float16)v[2 * t + 1]};
    const int lane = half * 32 + (n & 31);
    const int cg   = n >> 5;
    ws[ch * 512 + kh * 256 + cg * 64 + lane] = pk.q;
}

// ---------------- main: grid 1024, 4 batches/block, 4 waves, split accs ----------
__global__ __launch_bounds__(256, 2)
void CIN_main(const float* __restrict__ x,
              const char* __restrict__ wsB,
              const float* __restrict__ dw,
              const float* __restrict__ db,
              float* __restrict__ out)
{
    __shared__ __align__(16) _Float16 xsH[4 * XBB];    // [bb]: 16 rows of 72 (i<=39 used)
    __shared__ __align__(4)  _Float16 hsH[4][64][18];  // [bb][j][d]
    __shared__ float dws[192];
    __shared__ float red[4][4];

    const int tid  = threadIdx.x;
    const int w    = tid >> 6;     // col-quarter: n in [w*32, w*32+32)
    const int lane = tid & 63;
    const int half = lane >> 5;
    const int d    = lane & 15;
    const int bsel = (lane >> 4) & 1;
    const int col  = lane & 31;

    // B frag base; rebase +2048 so kh offsets {-2048,+2048} fit imm13
    const char* wbase = wsB + lane * 16 + w * 1024 + 2048;
    f16x8 Bb[4][2];                // [phase = ch&3][kh]
    auto loadBg = [&](int ch, f16x8 (&B)[2]) {
        const char* p0 = wbase + (size_t)ch * 8192;
        B[0] = *(const f16x8*)(p0 - 2048);
        B[1] = *(const f16x8*)(p0 + 2048);
    };

    loadBg(0, Bb[0]);
    loadBg(1, Bb[1]);
    loadBg(2, Bb[2]);
    loadBg(3, Bb[3]);

    // ---- stage x for 4 batches as f16 (624 float4, coalesced) ----
    const float4* xg4 = (const float4*)(x + (size_t)blockIdx.x * 4 * 624);
    for (int e4 = tid; e4 < 624; e4 += 256) {
        float4 v = xg4[e4];
        int bb = e4 / 156, r = e4 - bb * 156;
        int i = r >> 2, d0 = (r & 3) * 4;
        _Float16* bp = xsH + bb * XBB + i;
        bp[(d0 + 0) * 72] = (_Float16)v.x; bp[(d0 + 1) * 72] = (_Float16)v.y;
        bp[(d0 + 2) * 72] = (_Float16)v.z; bp[(d0 + 3) * 72] = (_Float16)v.w;
    }
    if (tid < 64) { int bb = tid >> 4, dd = tid & 15; xsH[bb * XBB + dd * 72 + 39] = (_Float16)0.f; }
    if (tid < 192) dws[tid] = dw[tid];
    __syncthreads();

    const _Float16* xrow[2] = {
        xsH + (0 * 2 + bsel) * XBB + d * 72,
        xsH + (1 * 2 + bsel) * XBB + d * 72
    };

    // ---- xw: the 40 halfs of x[0..39] per lane-batch, REGISTERS ----
    h2 xw[2][20];
#pragma unroll
    for (int p = 0; p < 2; ++p)
#pragma unroll
        for (int w5 = 0; w5 < 5; ++w5) {
            union { f16x8 v; h2 h[4]; } u;
            u.v = *(const f16x8*)(xrow[p] + w5 * 8);
#pragma unroll
            for (int q = 0; q < 4; ++q) xw[p][w5 * 4 + q] = u.h[q];
        }

    f32x16 accA[2], accB[2];       // SPLIT: kh=0 -> accA, kh=1 -> accB (independent)
#pragma unroll
    for (int p = 0; p < 2; ++p)
#pragma unroll
        for (int r = 0; r < 16; ++r) { accA[p][r] = 0.f; accB[p][r] = 0.f; }

    h2 sp2[2][2];

    // ---------------- layer 0: 30 folded chunks, fully unrolled, phase = c&3 ------
#pragma unroll
    for (int c = 0; c < L0C; ++c) {
        const int ig = IG0T(c);
        const int jg = JG0T(c);
        if ((c == 0) || (IG0T(c) != IG0T(c - 1))) {
#pragma unroll
            for (int p = 0; p < 2; ++p)
#pragma unroll
                for (int kh = 0; kh < 2; ++kh) {
                    const h2 pr = xw[p][ig * 2 + kh];
                    const _Float16 vv = half ? pr.y : pr.x;
                    sp2[p][kh] = h2{vv, vv};
                }
        }
#pragma unroll
        for (int p = 0; p < 2; ++p) {
            union { h2 h[4]; f16x8 v; } a0, a1;
#pragma unroll
            for (int q = 0; q < 4; ++q) {
                a0.h[q] = sp2[p][0] * xw[p][jg * 4 + q];   // v_pk_mul_f16
                a1.h[q] = sp2[p][1] * xw[p][jg * 4 + q];
            }
            accA[p] = __builtin_amdgcn_mfma_f32_32x32x16_f16(a0.v, Bb[c & 3][0], accA[p], 0, 0, 0);
            accB[p] = __builtin_amdgcn_mfma_f32_32x32x16_f16(a1.v, Bb[c & 3][1], accB[p], 0, 0, 0);
        }
        loadBg(c + 4, Bb[c & 3]);   // max 33 < 110; threads into L1 chunks 30..33
    }

    // ---------------- layer-0 epilogue (merge split accs, exact) ----------------
    float cs[4] = {0.f, 0.f, 0.f, 0.f};
    if (w < 2) {
#pragma unroll
        for (int p = 0; p < 2; ++p)
#pragma unroll
            for (int r = 0; r < 16; r += 2) {
                const int row = (r & 3) + 8 * (r >> 2) + 4 * half;
                h2 pr = h2{(_Float16)fmaxf(accA[p][r]     + accB[p][r],     0.f),
                           (_Float16)fmaxf(accA[p][r + 1] + accB[p][r + 1], 0.f)};
                *(h2*)&hsH[p * 2 + (row >> 4)][w * 32 + col][row & 15] = pr;
            }
    } else {
        const float dwv = dws[(w - 2) * 32 + col];      // dw[n-64]
#pragma unroll
        for (int p = 0; p < 2; ++p)
#pragma unroll
            for (int r = 0; r < 16; ++r) {
                const int row = (r & 3) + 8 * (r >> 2) + 4 * half;
                cs[p * 2 + (row >> 4)] += fmaxf(accA[p][r] + accB[p][r], 0.f) * dwv;
            }
    }
#pragma unroll
    for (int p = 0; p < 2; ++p)
#pragma unroll
        for (int r = 0; r < 16; ++r) { accA[p][r] = 0.f; accB[p][r] = 0.f; }
    __syncthreads();   // h visible to all waves

    // -------- layer 1: 4 outer x 20 unrolled chunks (30..109), phase=(2+u)&3 ------
#pragma unroll 1
    for (int o2 = 0; o2 < 4; ++o2) {
#pragma unroll
        for (int u = 0; u < 20; ++u) {
            const int ig2 = u % 5;
            if (ig2 == 0) {
                const int jb = (o2 * 4 + u / 5) * 4;
#pragma unroll
                for (int p = 0; p < 2; ++p)
#pragma unroll
                    for (int kh = 0; kh < 2; ++kh) {
                        const _Float16 s = hsH[p * 2 + bsel][jb + kh * 2 + half][d];
                        sp2[p][kh] = h2{s, s};
                    }
            }
#pragma unroll
            for (int p = 0; p < 2; ++p) {
                union { h2 h[4]; f16x8 v; } a0, a1;
#pragma unroll
                for (int q = 0; q < 4; ++q) {
                    a0.h[q] = sp2[p][0] * xw[p][ig2 * 4 + q];
                    a1.h[q] = sp2[p][1] * xw[p][ig2 * 4 + q];
                }
                accA[p] = __builtin_amdgcn_mfma_f32_32x32x16_f16(a0.v, Bb[(2 + u) & 3][0], accA[p], 0, 0, 0);
                accB[p] = __builtin_amdgcn_mfma_f32_32x32x16_f16(a1.v, Bb[(2 + u) & 3][1], accB[p], 0, 0, 0);
            }
            int chn = 30 + o2 * 20 + u + 4; if (chn > NCH - 1) chn = NCH - 1;
            loadBg(chn, Bb[(2 + u) & 3]);
        }
    }

    // ---------------- layer-1 epilogue + reduction ----------------
    {
        const float dwv = dws[64 + w * 32 + col];
#pragma unroll
        for (int p = 0; p < 2; ++p)
#pragma unroll
            for (int r = 0; r < 16; ++r) {
                const int row = (r & 3) + 8 * (r >> 2) + 4 * half;
                cs[p * 2 + (row >> 4)] += fmaxf(accA[p][r] + accB[p][r], 0.f) * dwv;
            }
    }
#pragma unroll
    for (int rr = 0; rr < 4; ++rr)
#pragma unroll
        for (int off = 32; off > 0; off >>= 1)
            cs[rr] += __shfl_xor(cs[rr], off, 64);
    if (lane == 0) {
#pragma unroll
        for (int rr = 0; rr < 4; ++rr) red[w][rr] = cs[rr];
    }
    __syncthreads();
    if (tid < 4)
        out[blockIdx.x * 4 + tid] = red[0][tid] + red[1][tid] + red[2][tid] + red[3][tid] + db[0];
}

extern "C" void kernel_launch(void* const* d_in, const int* in_sizes, int n_in,
                              void* d_out, int out_size, void* d_ws, size_t ws_size,
                              hipStream_t stream)
{
    const float* x  = (const float*)d_in[0];
    const float* f0 = (const float*)d_in[1];
    const float* f1 = (const float*)d_in[2];
    const float* dw = (const float*)d_in[3];
    const float* db = (const float*)d_in[4];
    float* out = (float*)d_out;

    CIN_repack<<<dim3(220), dim3(256), 0, stream>>>(f0, f1, (uint4*)d_ws);
    CIN_main<<<dim3(1024), dim3(256), 0, stream>>>(x, (const char*)d_ws, dw, db, out);
}